// Round 2
// baseline (200.000 us; speedup 1.0000x reference)
//
#include <hip/hip_runtime.h>

#define BATCH 262144
#define NI 9
#define NH 100
#define NO 2
#define T 25
#define BETA 0.95f
#define THR 1.0f

// One thread per batch element.
// Phase 1: per hidden unit h: cur1 = x·W1[h,:]+b1[h] (wave-uniform weights ->
//          s_loads), then the 25-step LIF recurrence with scalar mem1; each
//          step's spike accumulates W2[:,h] into per-step acc0[25]/acc1[25].
//          reset[t] == spk[t-1], so one compare per step.
// Phase 2: 25-step output LIF on accumulated currents, coalesced float2 stores.
//
// amdgpu_waves_per_eu(4,4): R1 showed the compiler targeting 8 waves/EU
// (VGPR_Count=32) and spilling the ~50 live accumulators to AGPRs
// (v_accvgpr round-trip = 3 VALU ops per acc update instead of 1).
// Grid is 4 blocks/CU = 16 waves/CU, so >4 waves/EU is unreachable anyway.
__global__
__attribute__((amdgpu_flat_work_group_size(256, 256), amdgpu_waves_per_eu(4, 4)))
void snn_fwd(
    const float* __restrict__ x,
    const float* __restrict__ W1,
    const float* __restrict__ b1,
    const float* __restrict__ W2,
    const float* __restrict__ b2,
    float* __restrict__ out)
{
    const int b = blockIdx.x * blockDim.x + threadIdx.x;
    if (b >= BATCH) return;

    float xi[NI];
#pragma unroll
    for (int i = 0; i < NI; ++i) xi[i] = x[(size_t)b * NI + i];

    float acc0[T], acc1[T];
#pragma unroll
    for (int t = 0; t < T; ++t) { acc0[t] = 0.0f; acc1[t] = 0.0f; }

    // Unroll by 2: two independent serial membrane chains in flight per lane.
#pragma unroll 2
    for (int h = 0; h < NH; ++h) {
        float c = xi[0] * W1[h * NI];
#pragma unroll
        for (int i = 1; i < NI; ++i) c = fmaf(xi[i], W1[h * NI + i], c);
        c += b1[h];

        const float w0 = W2[h];        // W2[0, h]
        const float w1 = W2[NH + h];   // W2[1, h]

        float mem = 0.0f, spk = 0.0f;  // spk doubles as next step's reset
#pragma unroll
        for (int t = 0; t < T; ++t) {
            mem = fmaf(BETA, mem, c) - spk;      // beta*mem + cur1 - reset*THR
            spk = (mem > THR) ? 1.0f : 0.0f;     // exact: (mem-1)>0 <=> mem>1
            acc0[t] = fmaf(spk, w0, acc0[t]);
            acc1[t] = fmaf(spk, w1, acc1[t]);
        }
    }

    const float b20 = b2[0], b21 = b2[1];
    float2* __restrict__ out_spk = (float2*)out;
    float2* __restrict__ out_mem = (float2*)(out + (size_t)T * BATCH * NO);

    float m0 = 0.0f, m1 = 0.0f, s0 = 0.0f, s1 = 0.0f;
#pragma unroll
    for (int t = 0; t < T; ++t) {
        const float c0 = acc0[t] + b20;
        const float c1 = acc1[t] + b21;
        m0 = fmaf(BETA, m0, c0) - s0;
        m1 = fmaf(BETA, m1, c1) - s1;
        s0 = (m0 > THR) ? 1.0f : 0.0f;
        s1 = (m1 > THR) ? 1.0f : 0.0f;
        out_spk[(size_t)t * BATCH + b] = make_float2(s0, s1);
        out_mem[(size_t)t * BATCH + b] = make_float2(m0, m1);
    }
}

extern "C" void kernel_launch(void* const* d_in, const int* in_sizes, int n_in,
                              void* d_out, int out_size, void* d_ws, size_t ws_size,
                              hipStream_t stream) {
    const float* x  = (const float*)d_in[0];
    const float* W1 = (const float*)d_in[1];
    const float* b1 = (const float*)d_in[2];
    const float* W2 = (const float*)d_in[3];
    const float* b2 = (const float*)d_in[4];
    float* out = (float*)d_out;

    dim3 block(256);
    dim3 grid(BATCH / 256);
    snn_fwd<<<grid, block, 0, stream>>>(x, W1, b1, W2, b2, out);
}

// Round 3
// 186.958 us; speedup vs baseline: 1.0698x; 1.0698x over previous
//
#include <hip/hip_runtime.h>

#define BATCH 262144
#define NI 9
#define NH 100
#define NO 2
#define T 25
#define BETA 0.95f
#define THR 1.0f

// One thread per batch element; h-outer / t-inner with per-step acc[25][2].
// reset[t] == spk[t-1] (reset is spike of carried membrane) -> 1 compare/step.
//
// R1/R2 post-mortem: RA kept the 50 long-lived acc values in AGPRs
// (unified file) and paid v_accvgpr_read/write around every update:
// 10.5 VALU/(h,t) instead of 6. Fix: inline-asm v_fmac with "+v" pins the
// accumulators to arch VGPRs; amdgpu_agpr_alloc(0) bans AGPRs where clang
// supports it.
#if defined(__has_attribute)
#  if __has_attribute(amdgpu_agpr_alloc)
#    define NO_AGPR __attribute__((amdgpu_agpr_alloc(0)))
#  else
#    define NO_AGPR
#  endif
#else
#  define NO_AGPR
#endif

__global__
__attribute__((amdgpu_flat_work_group_size(256, 256), amdgpu_waves_per_eu(4, 4)))
NO_AGPR
void snn_fwd(
    const float* __restrict__ x,
    const float* __restrict__ W1,
    const float* __restrict__ b1,
    const float* __restrict__ W2,
    const float* __restrict__ b2,
    float* __restrict__ out)
{
    const int b = blockIdx.x * blockDim.x + threadIdx.x;

    float xi[NI];
#pragma unroll
    for (int i = 0; i < NI; ++i) xi[i] = x[(size_t)b * NI + i];

    float acc0[T], acc1[T];
#pragma unroll
    for (int t = 0; t < T; ++t) { acc0[t] = 0.0f; acc1[t] = 0.0f; }

#pragma unroll 1
    for (int h = 0; h < NH; ++h) {
        // cur1 = dot(x, W1[h,:]) + b1[h]; weights are wave-uniform -> s_load.
        float c = xi[0] * W1[h * NI];
#pragma unroll
        for (int i = 1; i < NI; ++i) c = fmaf(xi[i], W1[h * NI + i], c);
        c += b1[h];

        const float w0 = W2[h];        // W2[0, h]
        const float w1 = W2[NH + h];   // W2[1, h]

        float mem = 0.0f, spk = 0.0f;  // spk doubles as next step's reset
#pragma unroll
        for (int t = 0; t < T; ++t) {
            mem = fmaf(BETA, mem, c) - spk;   // beta*mem + cur1 - reset*THR
            spk = (mem > THR) ? 1.0f : 0.0f;  // exact: (mem-1)>0 <=> mem>1
            // acc += spk * w  — pinned to arch VGPRs ("+v") so RA cannot
            // park acc0/acc1 in AGPRs with accvgpr round-trips per use.
            asm("v_fmac_f32 %0, %1, %2" : "+v"(acc0[t]) : "s"(w0), "v"(spk));
            asm("v_fmac_f32 %0, %1, %2" : "+v"(acc1[t]) : "s"(w1), "v"(spk));
        }
    }

    const float b20 = b2[0], b21 = b2[1];
    float2* __restrict__ out_spk = (float2*)out;
    float2* __restrict__ out_mem = (float2*)(out + (size_t)T * BATCH * NO);

    float m0 = 0.0f, m1 = 0.0f, s0 = 0.0f, s1 = 0.0f;
#pragma unroll
    for (int t = 0; t < T; ++t) {
        const float c0 = acc0[t] + b20;
        const float c1 = acc1[t] + b21;
        m0 = fmaf(BETA, m0, c0) - s0;
        m1 = fmaf(BETA, m1, c1) - s1;
        s0 = (m0 > THR) ? 1.0f : 0.0f;
        s1 = (m1 > THR) ? 1.0f : 0.0f;
        out_spk[(size_t)t * BATCH + b] = make_float2(s0, s1);
        out_mem[(size_t)t * BATCH + b] = make_float2(m0, m1);
    }
}

extern "C" void kernel_launch(void* const* d_in, const int* in_sizes, int n_in,
                              void* d_out, int out_size, void* d_ws, size_t ws_size,
                              hipStream_t stream) {
    const float* x  = (const float*)d_in[0];
    const float* W1 = (const float*)d_in[1];
    const float* b1 = (const float*)d_in[2];
    const float* W2 = (const float*)d_in[3];
    const float* b2 = (const float*)d_in[4];
    float* out = (float*)d_out;

    dim3 block(256);
    dim3 grid(BATCH / 256);
    snn_fwd<<<grid, block, 0, stream>>>(x, W1, b1, W2, b2, out);
}